// Round 16
// baseline (2539.990 us; speedup 1.0000x reference)
//
#include <hip/hip_runtime.h>
#include <hip/hip_bf16.h>
#include <math.h>

// ---------------- problem constants ----------------
#define BB 16
#define SS 289          // 1 cls + 288 selected tokens
#define DD 768
#define FFD 3072
#define NHD 12
#define NLAY 12
#define KSEL 288
#define NPATCH 576
#define MNTOT 3551232   // (BB*SS)*DD

typedef short bf16x8 __attribute__((ext_vector_type(8)));
typedef short bf16x4 __attribute__((ext_vector_type(4)));
typedef float f32x4 __attribute__((ext_vector_type(4)));

typedef __attribute__((address_space(3))) void lds_t;
typedef __attribute__((address_space(1))) const void glb_t;

__device__ __forceinline__ void gload16(const void* g, void* l) {
    __builtin_amdgcn_global_load_lds((glb_t*)g, (lds_t*)l, 16, 0, 0);
}

// inline-asm LDS read: invisible to compiler alias analysis, so no auto
// vmcnt(0) drain against outstanding global_load_lds (rule #18 discipline:
// caller must s_waitcnt lgkmcnt(0) + sched_barrier(0) before consuming).
__device__ __forceinline__ bf16x8 ds_read128(unsigned addr) {
    bf16x8 r;
    asm volatile("ds_read_b128 %0, %1" : "=v"(r) : "v"(addr));
    return r;
}

__device__ __forceinline__ float gelu_f(float v) {
    return 0.5f * v * (1.0f + erff(v * 0.70710678118654752f));
}

__device__ __forceinline__ void store_val(float* p, float v) { *p = v; }
__device__ __forceinline__ void store_val(__hip_bfloat16* p, float v) { *p = __float2bfloat16(v); }
__device__ __forceinline__ float load_f(const float* p) { return *p; }
__device__ __forceinline__ float load_f(const __hip_bfloat16* p) { return __bfloat162float(*p); }

// ---------------- patch pooling (channel 0, 16x16 mean) ----------------
__global__ __launch_bounds__(256) void pool_kernel(const float* __restrict__ x,
                                                   float* __restrict__ pooled) {
    int bp = blockIdx.x;
    int b = bp / NPATCH, p = bp - b * NPATCH;
    int gi = p / 24, gj = p - gi * 24;
    int tid = threadIdx.x;
    int pi = tid >> 4, pj = tid & 15;
    float v = x[((size_t)(b * 3) * 384 + gi * 16 + pi) * 384 + gj * 16 + pj];
    #pragma unroll
    for (int o = 32; o > 0; o >>= 1) v += __shfl_down(v, o);
    __shared__ float red[4];
    if ((tid & 63) == 0) red[tid >> 6] = v;
    __syncthreads();
    if (tid == 0) pooled[bp] = (red[0] + red[1] + red[2] + red[3]) * (1.0f / 256.0f);
}

// ---------------- exact stable top-k via rank counting ----------------
__global__ __launch_bounds__(576) void topk_kernel(const float* __restrict__ pooled,
                                                   int* __restrict__ idxsel) {
    __shared__ float a[NPATCH];
    int b = blockIdx.x, tid = threadIdx.x;
    a[tid] = fabsf(pooled[b * NPATCH + tid]);
    __syncthreads();
    float mine = a[tid];
    int rank = 0;
    for (int j = 0; j < NPATCH; ++j) {
        float aj = a[j];
        rank += (aj > mine) || (aj == mine && j < tid);
    }
    if (rank < KSEL) idxsel[b * KSEL + rank] = tid;
}

// ---------------- fp32 -> bf16 straight convert ----------------
__global__ __launch_bounds__(256) void convert_bf16(const float* __restrict__ in,
                                                    __hip_bfloat16* __restrict__ out,
                                                    int n) {
    int i = blockIdx.x * 256 + threadIdx.x;
    if (i < n) out[i] = __float2bfloat16(in[i]);
}

// ---------------- generic W[K][N] fp32 -> WT[N][K] bf16 (tiled transpose) ----------------
__global__ __launch_bounds__(256) void convert_w(const float* __restrict__ W,
                                                 __hip_bfloat16* __restrict__ O,
                                                 int K, int N) {
    __shared__ float tb[32][33];
    int ntx = N >> 5;
    int tile = blockIdx.x;
    int n0 = (tile % ntx) << 5, k0 = (tile / ntx) << 5;
    int t = threadIdx.x;
    int r = t >> 3, c = (t & 7) << 2;
    float4 v = *(const float4*)&W[(size_t)(k0 + r) * N + n0 + c];
    tb[r][c] = v.x; tb[r][c + 1] = v.y; tb[r][c + 2] = v.z; tb[r][c + 3] = v.w;
    __syncthreads();
    int n = t >> 3, k = (t & 7) << 2;
    __hip_bfloat16* dst = &O[(size_t)(n0 + n) * K + k0 + k];
    __hip_bfloat16 o4[4];
    #pragma unroll
    for (int j = 0; j < 4; ++j) o4[j] = __float2bfloat16(tb[k + j][n]);
    *(bf16x4*)dst = *(const bf16x4*)o4;
}

// ---------------- all 4 layer weights: fp32 [K][N] -> bf16 [N][K], one launch ----------------
__global__ __launch_bounds__(256) void convert_layer(const float* __restrict__ wqkv,
                                                     const float* __restrict__ wo,
                                                     const float* __restrict__ w1,
                                                     const float* __restrict__ w2,
                                                     __hip_bfloat16* __restrict__ oqkv,
                                                     __hip_bfloat16* __restrict__ owo,
                                                     __hip_bfloat16* __restrict__ ow1,
                                                     __hip_bfloat16* __restrict__ ow2) {
    __shared__ float tb[32][33];
    int bid = blockIdx.x;
    const float* W; __hip_bfloat16* O; int K, N, tile;
    if (bid < 1728)      { W = wqkv; O = oqkv; K = 768;  N = 2304; tile = bid; }
    else if (bid < 2304) { W = wo;   O = owo;  K = 768;  N = 768;  tile = bid - 1728; }
    else if (bid < 4608) { W = w1;   O = ow1;  K = 768;  N = 3072; tile = bid - 2304; }
    else                 { W = w2;   O = ow2;  K = 3072; N = 768;  tile = bid - 4608; }
    int ntx = N >> 5;
    int n0 = (tile % ntx) << 5, k0 = (tile / ntx) << 5;
    int t = threadIdx.x;
    int r = t >> 3, c = (t & 7) << 2;
    float4 v = *(const float4*)&W[(size_t)(k0 + r) * N + n0 + c];
    tb[r][c] = v.x; tb[r][c + 1] = v.y; tb[r][c + 2] = v.z; tb[r][c + 3] = v.w;
    __syncthreads();
    int n = t >> 3, k = (t & 7) << 2;
    __hip_bfloat16* dst = &O[(size_t)(n0 + n) * K + k0 + k];
    __hip_bfloat16 o4[4];
    #pragma unroll
    for (int j = 0; j < 4; ++j) o4[j] = __float2bfloat16(tb[k + j][n]);
    *(bf16x4*)dst = *(const bf16x4*)o4;
}

// ---------------- im2col of SELECTED patches only (bf16 out) ----------------
__global__ __launch_bounds__(256) void im2col_kernel(const float* __restrict__ x,
                                                     const int* __restrict__ idxsel,
                                                     __hip_bfloat16* __restrict__ col) {
    int t = blockIdx.x;
    int b = t / KSEL, r = t - b * KSEL;
    int p = idxsel[b * KSEL + r];
    int gi = p / 24, gj = p - gi * 24;
    int tid = threadIdx.x;
    int pi = tid >> 4, pj = tid & 15;
    __hip_bfloat16* crow = col + (size_t)t * 768;
    #pragma unroll
    for (int c = 0; c < 3; ++c)
        crow[c * 256 + tid] = __float2bfloat16(
            x[((size_t)(b * 3 + c) * 384 + gi * 16 + pi) * 384 + gj * 16 + pj]);
}

// ---------------- assemble h: cls + selected tokens + pos_emb (fp32) ----------------
__global__ __launch_bounds__(256) void assemble_tokens(const float* __restrict__ temp,
                                                       const float* __restrict__ cls_tok,
                                                       const float* __restrict__ pos_emb,
                                                       const int* __restrict__ idxsel,
                                                       float* __restrict__ h) {
    int row = blockIdx.x;
    int b = row / SS, s = row - b * SS;
    int tid = threadIdx.x;
    float* hrow = h + (size_t)row * DD;
    if (s == 0) {
        #pragma unroll
        for (int c = 0; c < 3; ++c) {
            int j = c * 256 + tid;
            hrow[j] = cls_tok[j] + pos_emb[j];
        }
    } else {
        int r = s - 1;
        int p = idxsel[b * KSEL + r];
        const float* trow = temp + (size_t)(b * KSEL + r) * DD;
        const float* pe = pos_emb + (size_t)(1 + p) * DD;
        #pragma unroll
        for (int c = 0; c < 3; ++c) {
            int j = c * 256 + tid;
            hrow[j] = trow[j] + pe[j];
        }
    }
}

// ---------------- LayerNorm over 768, templated output dtype ----------------
template <typename T>
__global__ __launch_bounds__(256) void ln_kernel(const float* __restrict__ in,
                                                 T* __restrict__ out,
                                                 const float* __restrict__ g,
                                                 const float* __restrict__ be,
                                                 size_t in_stride) {
    int row = blockIdx.x;
    const float* r = in + (size_t)row * in_stride;
    T* w = out + (size_t)row * DD;
    int tid = threadIdx.x;
    float v0 = r[tid], v1 = r[256 + tid], v2 = r[512 + tid];
    float s = v0 + v1 + v2;
    #pragma unroll
    for (int o = 32; o > 0; o >>= 1) s += __shfl_down(s, o);
    __shared__ float red[4];
    if ((tid & 63) == 0) red[tid >> 6] = s;
    __syncthreads();
    float mu = (red[0] + red[1] + red[2] + red[3]) * (1.0f / 768.0f);
    float d0 = v0 - mu, d1 = v1 - mu, d2 = v2 - mu;
    float q = d0 * d0 + d1 * d1 + d2 * d2;
    #pragma unroll
    for (int o = 32; o > 0; o >>= 1) q += __shfl_down(q, o);
    __syncthreads();
    if ((tid & 63) == 0) red[tid >> 6] = q;
    __syncthreads();
    float var = (red[0] + red[1] + red[2] + red[3]) * (1.0f / 768.0f);
    float rs = rsqrtf(var + 1e-6f);
    store_val(&w[tid],       d0 * rs * g[tid]       + be[tid]);
    store_val(&w[256 + tid], d1 * rs * g[256 + tid] + be[256 + tid]);
    store_val(&w[512 + tid], d2 * rs * g[512 + tid] + be[512 + tid]);
}

// ---------------- bf16 MFMA GEMM: C = A[M][K] @ BT[N][K]^T (exact R6 config) ----------------
// 128x256 tile, 8 waves (512 thr, 2x4 wave grid, each wave 64x64 out),
// BK=32, global_load_lds w=16, XOR swizzle both sides, 3 LDS buffers (72KB,
// 2 blocks/CU), depth-2 counted vmcnt(3), raw s_barrier, asm ds_read_b128.
// Best measured config; structural variants (R7/R9/R10) all regressed.
// SPLITK>1: blockIdx.z picks a K-chunk, raw partial written to part[z][M][N].
template <typename OUT_T, int ACT, int RES, int SPLITK>
__global__ __launch_bounds__(512) void gemm_bf16(const __hip_bfloat16* __restrict__ A,
                                                 const __hip_bfloat16* __restrict__ BT,
                                                 OUT_T* __restrict__ C,
                                                 const float* __restrict__ bias,
                                                 const float* __restrict__ res,
                                                 float* __restrict__ part,
                                                 int M, int N, int K) {
    __shared__ __hip_bfloat16 smA[3][128 * 32];   // 3 x 8KB
    __shared__ __hip_bfloat16 smB[3][256 * 32];   // 3 x 16KB
    const int t = threadIdx.x;
    const int lane = t & 63, wid = t >> 6;
    const int wr = wid >> 2, wc = wid & 3;        // 2x4 waves, 64x64 each
    const int l15 = lane & 15, l4 = lane >> 4;

    // XCD-chunked bijective swizzle over row-major linear block id (m204)
    const int gx = gridDim.x;
    const int nwg = gx * gridDim.y;
    const int orig = blockIdx.y * gx + blockIdx.x;
    const int q8 = nwg >> 3, r8 = nwg & 7;
    const int xcd = orig & 7, linb = orig >> 3;
    const int swz = (xcd < r8 ? xcd * (q8 + 1) : r8 * (q8 + 1) + (xcd - r8) * q8) + linb;
    const int m0 = (swz / gx) << 7;               // BM=128
    const int n0 = (swz - (swz / gx) * gx) << 8;  // BN=256

    const int Ksub = K / SPLITK;
    const int kz0 = blockIdx.z * Ksub;

    // fragment read byte offsets within one buffer (swizzled; row stride 64B)
    int ra[4], rb[4];
    #pragma unroll
    for (int f = 0; f < 4; ++f) {
        int ml = wr * 64 + f * 16 + l15;
        ra[f] = ml * 64 + ((l4 ^ ((ml >> 1) & 3)) << 4);
        int nl = wc * 64 + f * 16 + l15;
        rb[f] = nl * 64 + ((l4 ^ ((nl >> 1) & 3)) << 4);
    }

    // staging source offsets (inverse swizzle). A: 1 slot/thread; B: 2 slots.
    size_t aoff, boff[2];
    {
        int mA = t >> 2;
        int kcA = (t & 3) ^ ((mA >> 1) & 3);
        int gmA = m0 + mA; if (gmA > M - 1) gmA = M - 1;
        aoff = (size_t)gmA * K + kz0 + kcA * 8;
        #pragma unroll
        for (int it = 0; it < 2; ++it) {
            int s = it * 512 + t;
            int mB = s >> 2;
            int kc = (s & 3) ^ ((mB >> 1) & 3);
            boff[it] = (size_t)(n0 + mB) * K + kz0 + kc * 8;
        }
    }
    const int wb = wid << 10;                      // wave-uniform LDS base (1KB/wave)
    const unsigned ldsA0 = (unsigned)(size_t)(lds_t*)&smA[0][0];
    const unsigned ldsB0 = (unsigned)(size_t)(lds_t*)&smB[0][0];

    auto STAGE = [&](int kt, int buf) {
        int k0e = kt << 5;
        gload16(A + aoff + k0e,     (char*)(&smA[buf][0]) + wb);
        gload16(BT + boff[0] + k0e, (char*)(&smB[buf][0]) + wb);
        gload16(BT + boff[1] + k0e, (char*)(&smB[buf][0]) + 8192 + wb);
    };

    f32x4 acc[4][4];
    #pragma unroll
    for (int i = 0; i < 4; ++i)
        #pragma unroll
        for (int j = 0; j < 4; ++j) acc[i][j] = (f32x4){0.f, 0.f, 0.f, 0.f};

    const int nt = Ksub >> 5;                      // >= 12 for all our GEMMs
    STAGE(0, 0); STAGE(1, 1);
    int cur = 0, stb = 2;
    for (int kt = 0; kt < nt; ++kt) {
        if (kt + 1 < nt) asm volatile("s_waitcnt vmcnt(3)" ::: "memory");
        else             asm volatile("s_waitcnt vmcnt(0)" ::: "memory");
        asm volatile("s_barrier" ::: "memory");
        if (kt + 2 < nt) STAGE(kt + 2, stb);       // buf (kt+2)%3 == (kt-1)%3, readers drained
        const unsigned sa = ldsA0 + cur * 8192u;
        const unsigned sb = ldsB0 + cur * 16384u;
        bf16x8 af[4], bf[4];
        #pragma unroll
        for (int f = 0; f < 4; ++f) {
            af[f] = ds_read128(sa + ra[f]);
            bf[f] = ds_read128(sb + rb[f]);
        }
        asm volatile("s_waitcnt lgkmcnt(0)" ::: "memory");
        __builtin_amdgcn_sched_barrier(0);
        #pragma unroll
        for (int i = 0; i < 4; ++i)
            #pragma unroll
            for (int j = 0; j < 4; ++j)
                acc[i][j] = __builtin_amdgcn_mfma_f32_16x16x32_bf16(af[i], bf[j], acc[i][j], 0, 0, 0);
        cur = cur == 2 ? 0 : cur + 1;
        stb = stb == 2 ? 0 : stb + 1;
    }

    // epilogue
    if (SPLITK == 1) {
        #pragma unroll
        for (int i = 0; i < 4; ++i) {
            int gmb = m0 + wr * 64 + i * 16 + l4 * 4;
            #pragma unroll
            for (int j = 0; j < 4; ++j) {
                int gn = n0 + wc * 64 + j * 16 + l15;
                float bv = bias ? bias[gn] : 0.f;
                #pragma unroll
                for (int r = 0; r < 4; ++r) {
                    int gm = gmb + r;
                    if (gm < M) {
                        float v = acc[i][j][r] + bv;
                        if (ACT) v = gelu_f(v);
                        if (RES) v += res[(size_t)gm * N + gn];
                        store_val(&C[(size_t)gm * N + gn], v);
                    }
                }
            }
        }
    } else {
        float* pz = part + (size_t)blockIdx.z * M * N;
        #pragma unroll
        for (int i = 0; i < 4; ++i) {
            int gmb = m0 + wr * 64 + i * 16 + l4 * 4;
            #pragma unroll
            for (int j = 0; j < 4; ++j) {
                int gn = n0 + wc * 64 + j * 16 + l15;
                #pragma unroll
                for (int r = 0; r < 4; ++r) {
                    int gm = gmb + r;
                    if (gm < M) pz[(size_t)gm * N + gn] = acc[i][j][r];
                }
            }
        }
    }
}

// ---------------- fused split-K combine + residual + LayerNorm ----------------
// h[row] = h[row] + sum_z part[z][row] + bias;  out[row] = LN(h[row])*g + be.
template <int NPART>
__global__ __launch_bounds__(256) void combine_ln(const float* __restrict__ part,
                                                  const float* __restrict__ bias,
                                                  float* __restrict__ h,
                                                  const float* __restrict__ g,
                                                  const float* __restrict__ be,
                                                  __hip_bfloat16* __restrict__ out) {
    int row = blockIdx.x, tid = threadIdx.x;
    size_t base = (size_t)row * DD;
    float a[3];
    #pragma unroll
    for (int k = 0; k < 3; ++k) {
        int j = k * 256 + tid;
        float s = part[base + j];
        #pragma unroll
        for (int z = 1; z < NPART; ++z) s += part[(size_t)z * MNTOT + base + j];
        s += bias[j] + h[base + j];
        h[base + j] = s;
        a[k] = s;
    }
    float s = a[0] + a[1] + a[2];
    #pragma unroll
    for (int o = 32; o > 0; o >>= 1) s += __shfl_down(s, o);
    __shared__ float red[4];
    if ((tid & 63) == 0) red[tid >> 6] = s;
    __syncthreads();
    float mu = (red[0] + red[1] + red[2] + red[3]) * (1.0f / 768.0f);
    float d0 = a[0] - mu, d1 = a[1] - mu, d2 = a[2] - mu;
    float q = d0 * d0 + d1 * d1 + d2 * d2;
    #pragma unroll
    for (int o = 32; o > 0; o >>= 1) q += __shfl_down(q, o);
    __syncthreads();
    if ((tid & 63) == 0) red[tid >> 6] = q;
    __syncthreads();
    float var = (red[0] + red[1] + red[2] + red[3]) * (1.0f / 768.0f);
    float rs = rsqrtf(var + 1e-6f);
    out[base + tid]       = __float2bfloat16(d0 * rs * g[tid]       + be[tid]);
    out[base + 256 + tid] = __float2bfloat16(d1 * rs * g[256 + tid] + be[256 + tid]);
    out[base + 512 + tid] = __float2bfloat16(d2 * rs * g[512 + tid] + be[512 + tid]);
}

// ---------------- small 16-row GEMM (last-layer cls-only path) ----------------
// out[16][N] = (ACT?gelu:id)(A[16 rows] @ W[K][N] + bias) (+res).
// R16 fix: ONE block per 128-n chunk handles ALL 16 m rows (W read ONCE;
// R15's per-m grid re-read W up to 16x -> 93us/dispatch). A chunk staged to
// LDS transposed [k][16]; 512 thr = 128 n x 4 k-quarters; 16 accs/thread.
template <typename AT, int ACT, int RES>
__global__ __launch_bounds__(512) void small_gemm(const AT* __restrict__ A, size_t a_str,
                                                  const float* __restrict__ W,
                                                  const float* __restrict__ bias,
                                                  const float* __restrict__ res, size_t r_str,
                                                  float* __restrict__ out, int N, int K) {
    __shared__ float alds[768][16];    // 48KB: A chunk, transposed
    __shared__ float red[4][16][128];  // 32KB: cross-kq partials
    const int tid = threadIdx.x;
    const int nl = tid & 127, kq = tid >> 7;
    const int n = blockIdx.x * 128 + nl;
    float acc[16];
    #pragma unroll
    for (int m = 0; m < 16; ++m) acc[m] = 0.f;

    for (int c0 = 0; c0 < K; c0 += 768) {
        for (int i = tid; i < 16 * 768; i += 512) {
            int m = i / 768, k = i - m * 768;
            alds[k][m] = load_f(&A[(size_t)m * a_str + c0 + k]);
        }
        __syncthreads();
        if (n < N) {
            const float* wp = W + (size_t)(c0 + kq * 192) * N + n;
            #pragma unroll 2
            for (int k = 0; k < 192; ++k) {
                float w = wp[(size_t)k * N];
                const float* ap = &alds[kq * 192 + k][0];
                float4 a0 = *(const float4*)&ap[0];
                float4 a1 = *(const float4*)&ap[4];
                float4 a2 = *(const float4*)&ap[8];
                float4 a3 = *(const float4*)&ap[12];
                acc[0]  = fmaf(a0.x, w, acc[0]);  acc[1]  = fmaf(a0.y, w, acc[1]);
                acc[2]  = fmaf(a0.z, w, acc[2]);  acc[3]  = fmaf(a0.w, w, acc[3]);
                acc[4]  = fmaf(a1.x, w, acc[4]);  acc[5]  = fmaf(a1.y, w, acc[5]);
                acc[6]  = fmaf(a1.z, w, acc[6]);  acc[7]  = fmaf(a1.w, w, acc[7]);
                acc[8]  = fmaf(a2.x, w, acc[8]);  acc[9]  = fmaf(a2.y, w, acc[9]);
                acc[10] = fmaf(a2.z, w, acc[10]); acc[11] = fmaf(a2.w, w, acc[11]);
                acc[12] = fmaf(a3.x, w, acc[12]); acc[13] = fmaf(a3.y, w, acc[13]);
                acc[14] = fmaf(a3.z, w, acc[14]); acc[15] = fmaf(a3.w, w, acc[15]);
            }
        }
        __syncthreads();
    }

    #pragma unroll
    for (int m = 0; m < 16; ++m) red[kq][m][nl] = acc[m];
    __syncthreads();
    if (kq == 0 && n < N) {
        float bv = bias[n];
        #pragma unroll
        for (int m = 0; m < 16; ++m) {
            float v = red[0][m][nl] + red[1][m][nl] + red[2][m][nl] + red[3][m][nl] + bv;
            if (ACT) v = gelu_f(v);
            if (RES) v += res[(size_t)m * r_str + n];
            out[(size_t)m * N + n] = v;
        }
    }
}

// ---------------- classifier head: out[16][1000] = yf[16][768] @ fc_w + fc_b ----------------
__global__ __launch_bounds__(256) void head_gemm(const float* __restrict__ yf,
                                                 const float* __restrict__ fc_w,
                                                 const float* __restrict__ fc_b,
                                                 float* __restrict__ out) {
    __shared__ float part[128];
    const int tid = threadIdx.x;
    const int nl = tid & 127, kh = tid >> 7;
    const int m = blockIdx.y;
    const int n = blockIdx.x * 128 + nl;
    float acc = 0.f;
    if (n < 1000) {
        const float* yr = yf + (size_t)m * 768 + kh * 384;
        const float* wp = fc_w + (size_t)kh * 384 * 1000 + n;
        #pragma unroll 4
        for (int k = 0; k < 384; ++k)
            acc = fmaf(yr[k], wp[(size_t)k * 1000], acc);
    }
    if (kh == 1) part[nl] = acc;
    __syncthreads();
    if (kh == 0 && n < 1000)
        out[(size_t)m * 1000 + n] = acc + part[nl] + fc_b[n];
}

// ---------------- fused flash attention (bf16 MFMA, 1 wave per block) ----------------
__global__ __launch_bounds__(64) void attn_fused(const __hip_bfloat16* __restrict__ qkv,
                                                 __hip_bfloat16* __restrict__ o) {
    __shared__ __hip_bfloat16 p_lds[32][40];
    __shared__ __hip_bfloat16 v_lds[32][68];
    const int qt = blockIdx.x, bh = blockIdx.y;
    const int b = bh / NHD, hd = bh - b * NHD;
    const int lane = threadIdx.x;
    const int l15 = lane & 15, l4 = lane >> 4;
    const size_t tb = (size_t)b * SS;
    const int hc = hd * 64;

    bf16x8 aq[2][2];
    #pragma unroll
    for (int qi = 0; qi < 2; ++qi) {
        int qr = qt * 32 + qi * 16 + l15;
        if (qr >= SS) qr = SS - 1;
        const __hip_bfloat16* qrow = qkv + (tb + qr) * 2304 + hc;
        #pragma unroll
        for (int kd = 0; kd < 2; ++kd)
            aq[qi][kd] = *(const bf16x8*)(qrow + kd * 32 + l4 * 8);
    }

    float m_run[2][4], l_run[2][4];
    f32x4 oa[2][4];
    #pragma unroll
    for (int qi = 0; qi < 2; ++qi)
        #pragma unroll
        for (int r = 0; r < 4; ++r) { m_run[qi][r] = -1e30f; l_run[qi][r] = 0.f; }
    #pragma unroll
    for (int qi = 0; qi < 2; ++qi)
        #pragma unroll
        for (int dt = 0; dt < 4; ++dt) oa[qi][dt] = (f32x4){0.f, 0.f, 0.f, 0.f};

    for (int kt = 0; kt < 10; ++kt) {
        const int kbase = kt * 32;
        bf16x4 vreg[8];
        #pragma unroll
        for (int it = 0; it < 8; ++it) {
            int vr = kbase + it * 4 + l4;
            if (vr >= SS) vr = SS - 1;
            vreg[it] = *(const bf16x4*)(qkv + (tb + vr) * 2304 + 1536 + hc + l15 * 4);
        }
        bf16x8 bk[2][2];
        #pragma unroll
        for (int ki = 0; ki < 2; ++ki) {
            int kr = kbase + ki * 16 + l15;
            if (kr >= SS) kr = SS - 1;
            const __hip_bfloat16* krow = qkv + (tb + kr) * 2304 + 768 + hc;
            #pragma unroll
            for (int kd = 0; kd < 2; ++kd)
                bk[ki][kd] = *(const bf16x8*)(krow + kd * 32 + l4 * 8);
        }
        f32x4 s[2][2];
        #pragma unroll
        for (int qi = 0; qi < 2; ++qi)
            #pragma unroll
            for (int ki = 0; ki < 2; ++ki) {
                f32x4 a = (f32x4){0.f, 0.f, 0.f, 0.f};
                #pragma unroll
                for (int kd = 0; kd < 2; ++kd)
                    a = __builtin_amdgcn_mfma_f32_16x16x32_bf16(aq[qi][kd], bk[ki][kd], a, 0, 0, 0);
                s[qi][ki] = a;
            }
        #pragma unroll
        for (int ki = 0; ki < 2; ++ki) {
            bool valid = (kbase + ki * 16 + l15) < SS;
            #pragma unroll
            for (int qi = 0; qi < 2; ++qi)
                #pragma unroll
                for (int r = 0; r < 4; ++r)
                    s[qi][ki][r] = valid ? s[qi][ki][r] * 0.125f : -1e30f;
        }
        float p[2][2][4];
        #pragma unroll
        for (int qi = 0; qi < 2; ++qi) {
            float tm[4];
            #pragma unroll
            for (int r = 0; r < 4; ++r) tm[r] = fmaxf(s[qi][0][r], s[qi][1][r]);
            #pragma unroll
            for (int sh = 1; sh < 16; sh <<= 1)
                #pragma unroll
                for (int r = 0; r < 4; ++r) tm[r] = fmaxf(tm[r], __shfl_xor(tm[r], sh));
            float rs[4];
            #pragma unroll
            for (int r = 0; r < 4; ++r) {
                float mn = fmaxf(m_run[qi][r], tm[r]);
                float corr = __expf(m_run[qi][r] - mn);
                m_run[qi][r] = mn;
                float p0 = __expf(s[qi][0][r] - mn);
                float p1 = __expf(s[qi][1][r] - mn);
                p[qi][0][r] = p0; p[qi][1][r] = p1;
                rs[r] = p0 + p1;
                l_run[qi][r] *= corr;
                #pragma unroll
                for (int dt = 0; dt < 4; ++dt) oa[qi][dt][r] *= corr;
            }
            #pragma unroll
            for (int sh = 1; sh < 16; sh <<= 1)
                #pragma unroll
                for (int r = 0; r < 4; ++r) rs[r] += __shfl_xor(rs[r], sh);
            #pragma unroll
            for (int r = 0; r < 4; ++r) l_run[qi][r] += rs[r];
        }
        #pragma unroll
        for (int qi = 0; qi < 2; ++qi)
            #pragma unroll
            for (int ki = 0; ki < 2; ++ki)
                #pragma unroll
                for (int r = 0; r < 4; ++r)
                    p_lds[qi * 16 + l4 * 4 + r][ki * 16 + l15] = __float2bfloat16(p[qi][ki][r]);
        #pragma unroll
        for (int it = 0; it < 8; ++it)
            *(bf16x4*)&v_lds[it * 4 + l4][l15 * 4] = vreg[it];
        __syncthreads();
        bf16x8 pa[2];
        #pragma unroll
        for (int qi = 0; qi < 2; ++qi)
            pa[qi] = *(const bf16x8*)&p_lds[qi * 16 + l15][l4 * 8];
        bf16x8 vb[4];
        #pragma unroll
        for (int dt = 0; dt < 4; ++dt) {
            bf16x8 v;
            #pragma unroll
            for (int j = 0; j < 8; ++j)
                v[j] = *(const short*)&v_lds[l4 * 8 + j][dt * 16 + l15];
            vb[dt] = v;
        }
        #pragma unroll
        for (int qi = 0; qi < 2; ++qi)
            #pragma unroll
            for (int dt = 0; dt < 4; ++dt)
                oa[qi][dt] = __builtin_amdgcn_mfma_f32_16x16x32_bf16(pa[qi], vb[dt], oa[qi][dt], 0, 0, 0);
        __syncthreads();
    }
    #pragma unroll
    for (int qi = 0; qi < 2; ++qi)
        #pragma unroll
        for (int r = 0; r < 4; ++r) {
            int q = qt * 32 + qi * 16 + l4 * 4 + r;
            if (q < SS) {
                float inv = 1.0f / l_run[qi][r];
                __hip_bfloat16* orow = o + (tb + q) * 768 + hc;
                #pragma unroll
                for (int dt = 0; dt < 4; ++dt)
                    orow[dt * 16 + l15] = __float2bfloat16(oa[qi][dt][r] * inv);
            }
        }
}

// ---------------- workspace layout (float offsets) ----------------
static const size_t OFF_POOLED = 0;           //  9216 f
static const size_t OFF_IDX    = 10240;       //  4608 int
static const size_t OFF_H      = 16384;       //  3,551,232 f
static const size_t OFF_YB     = 3567616;     //  3,551,232 bf16 (1,775,616 f)
static const size_t OFF_OB     = 5343232;     //  3,551,232 bf16
static const size_t OFF_QKVB   = 7118848;     // 10,653,696 bf16 (5,326,848 f)
static const size_t OFF_WBUF   = 12445696;    //  7,077,888 bf16 (3,538,944 f)
static const size_t OFF_PWB    = 15984640;    //    589,824 bf16 (294,912 f)
static const size_t OFF_YF     = 16279552;    //     12,288 f
static const size_t OFF_BIG    = 16291840;    //  7,102,464 f (col+temp / hidden)
static const size_t OFF_PART   = 23394304;    // 14,204,928 f (4 x M*N split-K partials)
static const size_t OFF_SMALL  = 37599232;    //     86,016 f (last-layer cls-only path)
// total 37,685,248 floats = 150.7 MB

extern "C" void kernel_launch(void* const* d_in, const int* in_sizes, int n_in,
                              void* d_out, int out_size, void* d_ws, size_t ws_size,
                              hipStream_t stream) {
    const float* x       = (const float*)d_in[0];
    const float* patch_w = (const float*)d_in[1];
    const float* patch_b = (const float*)d_in[2];
    const float* cls_tok = (const float*)d_in[3];
    const float* pos_emb = (const float*)d_in[4];
    const float* ln1_g   = (const float*)d_in[5];
    const float* ln1_b   = (const float*)d_in[6];
    const float* Wqkv    = (const float*)d_in[7];
    const float* bqkv    = (const float*)d_in[8];
    const float* Wo      = (const float*)d_in[9];
    const float* bo      = (const float*)d_in[10];
    const float* ln2_g   = (const float*)d_in[11];
    const float* ln2_b   = (const float*)d_in[12];
    const float* W1      = (const float*)d_in[13];
    const float* b1      = (const float*)d_in[14];
    const float* W2      = (const float*)d_in[15];
    const float* b2      = (const float*)d_in[16];
    const float* lnf_g   = (const float*)d_in[17];
    const float* lnf_b   = (const float*)d_in[18];
    const float* fc_w    = (const float*)d_in[19];
    const float* fc_b    = (const float*)d_in[20];
    float* out = (float*)d_out;
    float* ws  = (float*)d_ws;

    float*          pooled = ws + OFF_POOLED;
    int*            idxsel = (int*)(ws + OFF_IDX);
    float*          h      = ws + OFF_H;
    __hip_bfloat16* yb     = (__hip_bfloat16*)(ws + OFF_YB);
    __hip_bfloat16* ob     = (__hip_bfloat16*)(ws + OFF_OB);
    __hip_bfloat16* qkvb   = (__hip_bfloat16*)(ws + OFF_QKVB);
    __hip_bfloat16* wbuf   = (__hip_bfloat16*)(ws + OFF_WBUF);
    __hip_bfloat16* pwb    = (__hip_bfloat16*)(ws + OFF_PWB);
    float*          yf     = ws + OFF_YF;
    float*          big    = ws + OFF_BIG;
    float*          part   = ws + OFF_PART;
    float*          sm     = ws + OFF_SMALL;
    __hip_bfloat16* col    = (__hip_bfloat16*)big;             // 3,538,944 bf16
    float*          temp   = big + 1769472;                    // 3,538,944 f
    __hip_bfloat16* hidden = (__hip_bfloat16*)big;             // 14,204,928 bf16

    __hip_bfloat16* wqkvT = wbuf;                              // [2304][768]
    __hip_bfloat16* woT   = wbuf + 1769472;                    // [768][768]
    __hip_bfloat16* w1T   = wbuf + 2359296;                    // [3072][768]
    __hip_bfloat16* w2T   = wbuf + 4718592;                    // [768][3072]

    // last-layer small buffers (float offsets inside sm)
    float* h_cls   = sm;               // 16x768
    float* y_cls   = sm + 12288;       // 16x768
    float* hid_cls = sm + 24576;       // 16x3072
    float* hfin    = sm + 73728;       // 16x768

    const int M = BB * SS;            // 4624
    const int MG = 37;                // ceil(4624/128)

    // ---- sparse selection + patch embedding ----
    pool_kernel<<<BB * NPATCH, 256, 0, stream>>>(x, pooled);
    topk_kernel<<<BB, 576, 0, stream>>>(pooled, idxsel);
    convert_bf16<<<(589824 + 255) / 256, 256, 0, stream>>>(patch_w, pwb, 589824);
    im2col_kernel<<<BB * KSEL, 256, 0, stream>>>(x, idxsel, col);
    gemm_bf16<float, 0, 0, 1><<<dim3(3, 36), 512, 0, stream>>>(
        col, pwb, temp, patch_b, nullptr, nullptr, 4608, DD, DD);
    assemble_tokens<<<BB * SS, 256, 0, stream>>>(temp, cls_tok, pos_emb, idxsel, h);

    // ln1 for layer 0 (subsequent layers get it fused into the W2 combine)
    ln_kernel<__hip_bfloat16><<<M, 256, 0, stream>>>(h, yb, ln1_g, ln1_b, DD);

    // ---- transformer layers 0..10 (full) ----
    for (int i = 0; i < NLAY - 1; ++i) {
        convert_layer<<<6912, 256, 0, stream>>>(Wqkv + (size_t)i * DD * 3 * DD,
                                                Wo + (size_t)i * DD * DD,
                                                W1 + (size_t)i * DD * FFD,
                                                W2 + (size_t)i * FFD * DD,
                                                wqkvT, woT, w1T, w2T);

        gemm_bf16<__hip_bfloat16, 0, 0, 1><<<dim3(9, MG), 512, 0, stream>>>(
            yb, wqkvT, qkvb, bqkv + (size_t)i * 3 * DD, nullptr, nullptr, M, 3 * DD, DD);
        attn_fused<<<dim3(10, BB * NHD), 64, 0, stream>>>(qkvb, ob);
        // Wo: split-K x2 -> partials; fused combine(+bias+residual)+LN2 -> yb
        gemm_bf16<float, 0, 0, 2><<<dim3(3, MG, 2), 512, 0, stream>>>(
            ob, woT, (float*)nullptr, nullptr, nullptr, part, M, DD, DD);
        combine_ln<2><<<M, 256, 0, stream>>>(part, bo + (size_t)i * DD, h,
                                             ln2_g + (size_t)i * DD, ln2_b + (size_t)i * DD, yb);
        gemm_bf16<__hip_bfloat16, 1, 0, 1><<<dim3(12, MG), 512, 0, stream>>>(
            yb, w1T, hidden, b1 + (size_t)i * FFD, nullptr, nullptr, M, FFD, DD);
        // W2: split-K x4 -> partials; fused combine+LN1(next layer) -> yb
        gemm_bf16<float, 0, 0, 4><<<dim3(3, MG, 4), 512, 0, stream>>>(
            hidden, w2T, (float*)nullptr, nullptr, nullptr, part, M, DD, FFD);
        combine_ln<4><<<M, 256, 0, stream>>>(part, b2 + (size_t)i * DD, h,
                                             ln1_g + (size_t)(i + 1) * DD,
                                             ln1_b + (size_t)(i + 1) * DD, yb);
    }

    // ---- layer 11: after QKV, only cls rows are live (output reads LN(h)[:,0]) ----
    {
        const int L = NLAY - 1;
        convert_w<<<72 * 24, 256, 0, stream>>>(Wqkv + (size_t)L * DD * 3 * DD, wqkvT, DD, 3 * DD);
        gemm_bf16<__hip_bfloat16, 0, 0, 1><<<dim3(9, MG), 512, 0, stream>>>(
            yb, wqkvT, qkvb, bqkv + (size_t)L * 3 * DD, nullptr, nullptr, M, 3 * DD, DD);
        // attention: only q-tile 0 (contains cls row of every batch/head)
        attn_fused<<<dim3(1, BB * NHD), 64, 0, stream>>>(qkvb, ob);
        // Wo on 16 cls rows (original fp32 weights; W read once per block)
        small_gemm<__hip_bfloat16, 0, 1><<<6, 512, 0, stream>>>(
            ob, (size_t)SS * DD, Wo + (size_t)L * DD * DD, bo + (size_t)L * DD,
            h, (size_t)SS * DD, h_cls, DD, DD);
        ln_kernel<float><<<16, 256, 0, stream>>>(h_cls, y_cls, ln2_g + (size_t)L * DD,
                                                 ln2_b + (size_t)L * DD, DD);
        small_gemm<float, 1, 0><<<24, 512, 0, stream>>>(
            y_cls, DD, W1 + (size_t)L * DD * FFD, b1 + (size_t)L * FFD,
            nullptr, 0, hid_cls, FFD, DD);
        small_gemm<float, 0, 1><<<6, 512, 0, stream>>>(
            hid_cls, FFD, W2 + (size_t)L * FFD * DD, b2 + (size_t)L * DD,
            h_cls, DD, hfin, DD, FFD);
    }

    // ---- final LN on cls rows + classifier head ----
    ln_kernel<float><<<16, 256, 0, stream>>>(hfin, yf, lnf_g, lnf_b, DD);
    head_gemm<<<dim3(8, 16), 256, 0, stream>>>(yf, fc_w, fc_b, out);
}

// Round 17
// 2337.349 us; speedup vs baseline: 1.0867x; 1.0867x over previous
//
#include <hip/hip_runtime.h>
#include <hip/hip_bf16.h>
#include <math.h>

// ---------------- problem constants ----------------
#define BB 16
#define SS 289          // 1 cls + 288 selected tokens
#define DD 768
#define FFD 3072
#define NHD 12
#define NLAY 12
#define KSEL 288
#define NPATCH 576
#define MNTOT 3551232   // (BB*SS)*DD

typedef short bf16x8 __attribute__((ext_vector_type(8)));
typedef short bf16x4 __attribute__((ext_vector_type(4)));
typedef float f32x4 __attribute__((ext_vector_type(4)));

typedef __attribute__((address_space(3))) void lds_t;
typedef __attribute__((address_space(1))) const void glb_t;

__device__ __forceinline__ void gload16(const void* g, void* l) {
    __builtin_amdgcn_global_load_lds((glb_t*)g, (lds_t*)l, 16, 0, 0);
}

// inline-asm LDS read: invisible to compiler alias analysis, so no auto
// vmcnt(0) drain against outstanding global_load_lds (rule #18 discipline:
// caller must s_waitcnt lgkmcnt(0) + sched_barrier(0) before consuming).
__device__ __forceinline__ bf16x8 ds_read128(unsigned addr) {
    bf16x8 r;
    asm volatile("ds_read_b128 %0, %1" : "=v"(r) : "v"(addr));
    return r;
}

__device__ __forceinline__ float gelu_f(float v) {
    return 0.5f * v * (1.0f + erff(v * 0.70710678118654752f));
}

__device__ __forceinline__ void store_val(float* p, float v) { *p = v; }
__device__ __forceinline__ void store_val(__hip_bfloat16* p, float v) { *p = __float2bfloat16(v); }

// ---------------- patch pooling (channel 0, 16x16 mean) ----------------
__global__ __launch_bounds__(256) void pool_kernel(const float* __restrict__ x,
                                                   float* __restrict__ pooled) {
    int bp = blockIdx.x;
    int b = bp / NPATCH, p = bp - b * NPATCH;
    int gi = p / 24, gj = p - gi * 24;
    int tid = threadIdx.x;
    int pi = tid >> 4, pj = tid & 15;
    float v = x[((size_t)(b * 3) * 384 + gi * 16 + pi) * 384 + gj * 16 + pj];
    #pragma unroll
    for (int o = 32; o > 0; o >>= 1) v += __shfl_down(v, o);
    __shared__ float red[4];
    if ((tid & 63) == 0) red[tid >> 6] = v;
    __syncthreads();
    if (tid == 0) pooled[bp] = (red[0] + red[1] + red[2] + red[3]) * (1.0f / 256.0f);
}

// ---------------- exact stable top-k via rank counting ----------------
__global__ __launch_bounds__(576) void topk_kernel(const float* __restrict__ pooled,
                                                   int* __restrict__ idxsel) {
    __shared__ float a[NPATCH];
    int b = blockIdx.x, tid = threadIdx.x;
    a[tid] = fabsf(pooled[b * NPATCH + tid]);
    __syncthreads();
    float mine = a[tid];
    int rank = 0;
    for (int j = 0; j < NPATCH; ++j) {
        float aj = a[j];
        rank += (aj > mine) || (aj == mine && j < tid);
    }
    if (rank < KSEL) idxsel[b * KSEL + rank] = tid;
}

// ---------------- fp32 -> bf16 straight convert ----------------
__global__ __launch_bounds__(256) void convert_bf16(const float* __restrict__ in,
                                                    __hip_bfloat16* __restrict__ out,
                                                    int n) {
    int i = blockIdx.x * 256 + threadIdx.x;
    if (i < n) out[i] = __float2bfloat16(in[i]);
}

// ---------------- all 4 layer weights: fp32 [K][N] -> bf16 [N][K], one launch ----------------
__global__ __launch_bounds__(256) void convert_layer(const float* __restrict__ wqkv,
                                                     const float* __restrict__ wo,
                                                     const float* __restrict__ w1,
                                                     const float* __restrict__ w2,
                                                     __hip_bfloat16* __restrict__ oqkv,
                                                     __hip_bfloat16* __restrict__ owo,
                                                     __hip_bfloat16* __restrict__ ow1,
                                                     __hip_bfloat16* __restrict__ ow2) {
    __shared__ float tb[32][33];
    int bid = blockIdx.x;
    const float* W; __hip_bfloat16* O; int K, N, tile;
    if (bid < 1728)      { W = wqkv; O = oqkv; K = 768;  N = 2304; tile = bid; }
    else if (bid < 2304) { W = wo;   O = owo;  K = 768;  N = 768;  tile = bid - 1728; }
    else if (bid < 4608) { W = w1;   O = ow1;  K = 768;  N = 3072; tile = bid - 2304; }
    else                 { W = w2;   O = ow2;  K = 3072; N = 768;  tile = bid - 4608; }
    int ntx = N >> 5;
    int n0 = (tile % ntx) << 5, k0 = (tile / ntx) << 5;
    int t = threadIdx.x;
    int r = t >> 3, c = (t & 7) << 2;
    float4 v = *(const float4*)&W[(size_t)(k0 + r) * N + n0 + c];
    tb[r][c] = v.x; tb[r][c + 1] = v.y; tb[r][c + 2] = v.z; tb[r][c + 3] = v.w;
    __syncthreads();
    int n = t >> 3, k = (t & 7) << 2;
    __hip_bfloat16* dst = &O[(size_t)(n0 + n) * K + k0 + k];
    __hip_bfloat16 o4[4];
    #pragma unroll
    for (int j = 0; j < 4; ++j) o4[j] = __float2bfloat16(tb[k + j][n]);
    *(bf16x4*)dst = *(const bf16x4*)o4;
}

// ---------------- im2col of SELECTED patches only (bf16 out) ----------------
__global__ __launch_bounds__(256) void im2col_kernel(const float* __restrict__ x,
                                                     const int* __restrict__ idxsel,
                                                     __hip_bfloat16* __restrict__ col) {
    int t = blockIdx.x;
    int b = t / KSEL, r = t - b * KSEL;
    int p = idxsel[b * KSEL + r];
    int gi = p / 24, gj = p - gi * 24;
    int tid = threadIdx.x;
    int pi = tid >> 4, pj = tid & 15;
    __hip_bfloat16* crow = col + (size_t)t * 768;
    #pragma unroll
    for (int c = 0; c < 3; ++c)
        crow[c * 256 + tid] = __float2bfloat16(
            x[((size_t)(b * 3 + c) * 384 + gi * 16 + pi) * 384 + gj * 16 + pj]);
}

// ---------------- assemble h: cls + selected tokens + pos_emb (fp32) ----------------
__global__ __launch_bounds__(256) void assemble_tokens(const float* __restrict__ temp,
                                                       const float* __restrict__ cls_tok,
                                                       const float* __restrict__ pos_emb,
                                                       const int* __restrict__ idxsel,
                                                       float* __restrict__ h) {
    int row = blockIdx.x;
    int b = row / SS, s = row - b * SS;
    int tid = threadIdx.x;
    float* hrow = h + (size_t)row * DD;
    if (s == 0) {
        #pragma unroll
        for (int c = 0; c < 3; ++c) {
            int j = c * 256 + tid;
            hrow[j] = cls_tok[j] + pos_emb[j];
        }
    } else {
        int r = s - 1;
        int p = idxsel[b * KSEL + r];
        const float* trow = temp + (size_t)(b * KSEL + r) * DD;
        const float* pe = pos_emb + (size_t)(1 + p) * DD;
        #pragma unroll
        for (int c = 0; c < 3; ++c) {
            int j = c * 256 + tid;
            hrow[j] = trow[j] + pe[j];
        }
    }
}

// ---------------- LayerNorm over 768, templated output dtype ----------------
template <typename T>
__global__ __launch_bounds__(256) void ln_kernel(const float* __restrict__ in,
                                                 T* __restrict__ out,
                                                 const float* __restrict__ g,
                                                 const float* __restrict__ be,
                                                 size_t in_stride) {
    int row = blockIdx.x;
    const float* r = in + (size_t)row * in_stride;
    T* w = out + (size_t)row * DD;
    int tid = threadIdx.x;
    float v0 = r[tid], v1 = r[256 + tid], v2 = r[512 + tid];
    float s = v0 + v1 + v2;
    #pragma unroll
    for (int o = 32; o > 0; o >>= 1) s += __shfl_down(s, o);
    __shared__ float red[4];
    if ((tid & 63) == 0) red[tid >> 6] = s;
    __syncthreads();
    float mu = (red[0] + red[1] + red[2] + red[3]) * (1.0f / 768.0f);
    float d0 = v0 - mu, d1 = v1 - mu, d2 = v2 - mu;
    float q = d0 * d0 + d1 * d1 + d2 * d2;
    #pragma unroll
    for (int o = 32; o > 0; o >>= 1) q += __shfl_down(q, o);
    __syncthreads();
    if ((tid & 63) == 0) red[tid >> 6] = q;
    __syncthreads();
    float var = (red[0] + red[1] + red[2] + red[3]) * (1.0f / 768.0f);
    float rs = rsqrtf(var + 1e-6f);
    store_val(&w[tid],       d0 * rs * g[tid]       + be[tid]);
    store_val(&w[256 + tid], d1 * rs * g[256 + tid] + be[256 + tid]);
    store_val(&w[512 + tid], d2 * rs * g[512 + tid] + be[512 + tid]);
}

// ---------------- bf16 MFMA GEMM: C = A[M][K] @ BT[N][K]^T (exact R6 config) ----------------
// 128x256 tile, 8 waves (512 thr, 2x4 wave grid, each wave 64x64 out),
// BK=32, global_load_lds w=16, XOR swizzle both sides, 3 LDS buffers (72KB,
// 2 blocks/CU), depth-2 counted vmcnt(3), raw s_barrier, asm ds_read_b128.
// Best measured config; structural variants (R7/R9/R10) and GEMV paths
// (R15/R16) all regressed.
// SPLITK>1: blockIdx.z picks a K-chunk, raw partial written to part[z][M][N].
template <typename OUT_T, int ACT, int RES, int SPLITK>
__global__ __launch_bounds__(512) void gemm_bf16(const __hip_bfloat16* __restrict__ A,
                                                 const __hip_bfloat16* __restrict__ BT,
                                                 OUT_T* __restrict__ C,
                                                 const float* __restrict__ bias,
                                                 const float* __restrict__ res,
                                                 float* __restrict__ part,
                                                 int M, int N, int K) {
    __shared__ __hip_bfloat16 smA[3][128 * 32];   // 3 x 8KB
    __shared__ __hip_bfloat16 smB[3][256 * 32];   // 3 x 16KB
    const int t = threadIdx.x;
    const int lane = t & 63, wid = t >> 6;
    const int wr = wid >> 2, wc = wid & 3;        // 2x4 waves, 64x64 each
    const int l15 = lane & 15, l4 = lane >> 4;

    // XCD-chunked bijective swizzle over row-major linear block id (m204)
    const int gx = gridDim.x;
    const int nwg = gx * gridDim.y;
    const int orig = blockIdx.y * gx + blockIdx.x;
    const int q8 = nwg >> 3, r8 = nwg & 7;
    const int xcd = orig & 7, linb = orig >> 3;
    const int swz = (xcd < r8 ? xcd * (q8 + 1) : r8 * (q8 + 1) + (xcd - r8) * q8) + linb;
    const int m0 = (swz / gx) << 7;               // BM=128
    const int n0 = (swz - (swz / gx) * gx) << 8;  // BN=256

    const int Ksub = K / SPLITK;
    const int kz0 = blockIdx.z * Ksub;

    // fragment read byte offsets within one buffer (swizzled; row stride 64B)
    int ra[4], rb[4];
    #pragma unroll
    for (int f = 0; f < 4; ++f) {
        int ml = wr * 64 + f * 16 + l15;
        ra[f] = ml * 64 + ((l4 ^ ((ml >> 1) & 3)) << 4);
        int nl = wc * 64 + f * 16 + l15;
        rb[f] = nl * 64 + ((l4 ^ ((nl >> 1) & 3)) << 4);
    }

    // staging source offsets (inverse swizzle). A: 1 slot/thread; B: 2 slots.
    size_t aoff, boff[2];
    {
        int mA = t >> 2;
        int kcA = (t & 3) ^ ((mA >> 1) & 3);
        int gmA = m0 + mA; if (gmA > M - 1) gmA = M - 1;
        aoff = (size_t)gmA * K + kz0 + kcA * 8;
        #pragma unroll
        for (int it = 0; it < 2; ++it) {
            int s = it * 512 + t;
            int mB = s >> 2;
            int kc = (s & 3) ^ ((mB >> 1) & 3);
            boff[it] = (size_t)(n0 + mB) * K + kz0 + kc * 8;
        }
    }
    const int wb = wid << 10;                      // wave-uniform LDS base (1KB/wave)
    const unsigned ldsA0 = (unsigned)(size_t)(lds_t*)&smA[0][0];
    const unsigned ldsB0 = (unsigned)(size_t)(lds_t*)&smB[0][0];

    auto STAGE = [&](int kt, int buf) {
        int k0e = kt << 5;
        gload16(A + aoff + k0e,     (char*)(&smA[buf][0]) + wb);
        gload16(BT + boff[0] + k0e, (char*)(&smB[buf][0]) + wb);
        gload16(BT + boff[1] + k0e, (char*)(&smB[buf][0]) + 8192 + wb);
    };

    f32x4 acc[4][4];
    #pragma unroll
    for (int i = 0; i < 4; ++i)
        #pragma unroll
        for (int j = 0; j < 4; ++j) acc[i][j] = (f32x4){0.f, 0.f, 0.f, 0.f};

    const int nt = Ksub >> 5;                      // >= 12 for all our GEMMs
    STAGE(0, 0); STAGE(1, 1);
    int cur = 0, stb = 2;
    for (int kt = 0; kt < nt; ++kt) {
        if (kt + 1 < nt) asm volatile("s_waitcnt vmcnt(3)" ::: "memory");
        else             asm volatile("s_waitcnt vmcnt(0)" ::: "memory");
        asm volatile("s_barrier" ::: "memory");
        if (kt + 2 < nt) STAGE(kt + 2, stb);       // buf (kt+2)%3 == (kt-1)%3, readers drained
        const unsigned sa = ldsA0 + cur * 8192u;
        const unsigned sb = ldsB0 + cur * 16384u;
        bf16x8 af[4], bf[4];
        #pragma unroll
        for (int f = 0; f < 4; ++f) {
            af[f] = ds_read128(sa + ra[f]);
            bf[f] = ds_read128(sb + rb[f]);
        }
        asm volatile("s_waitcnt lgkmcnt(0)" ::: "memory");
        __builtin_amdgcn_sched_barrier(0);
        #pragma unroll
        for (int i = 0; i < 4; ++i)
            #pragma unroll
            for (int j = 0; j < 4; ++j)
                acc[i][j] = __builtin_amdgcn_mfma_f32_16x16x32_bf16(af[i], bf[j], acc[i][j], 0, 0, 0);
        cur = cur == 2 ? 0 : cur + 1;
        stb = stb == 2 ? 0 : stb + 1;
    }

    // epilogue
    if (SPLITK == 1) {
        #pragma unroll
        for (int i = 0; i < 4; ++i) {
            int gmb = m0 + wr * 64 + i * 16 + l4 * 4;
            #pragma unroll
            for (int j = 0; j < 4; ++j) {
                int gn = n0 + wc * 64 + j * 16 + l15;
                float bv = bias ? bias[gn] : 0.f;
                #pragma unroll
                for (int r = 0; r < 4; ++r) {
                    int gm = gmb + r;
                    if (gm < M) {
                        float v = acc[i][j][r] + bv;
                        if (ACT) v = gelu_f(v);
                        if (RES) v += res[(size_t)gm * N + gn];
                        store_val(&C[(size_t)gm * N + gn], v);
                    }
                }
            }
        }
    } else {
        float* pz = part + (size_t)blockIdx.z * M * N;
        #pragma unroll
        for (int i = 0; i < 4; ++i) {
            int gmb = m0 + wr * 64 + i * 16 + l4 * 4;
            #pragma unroll
            for (int j = 0; j < 4; ++j) {
                int gn = n0 + wc * 64 + j * 16 + l15;
                #pragma unroll
                for (int r = 0; r < 4; ++r) {
                    int gm = gmb + r;
                    if (gm < M) pz[(size_t)gm * N + gn] = acc[i][j][r];
                }
            }
        }
    }
}

// ---------------- split-K combine (plain): h += sum_z part[z] + bias ----------------
template <int NPART>
__global__ __launch_bounds__(256) void combine_res(const float* __restrict__ part,
                                                   const float* __restrict__ bias,
                                                   float* __restrict__ h,
                                                   int MN, int N) {
    int i = (blockIdx.x * 256 + threadIdx.x) * 4;
    if (i >= MN) return;
    float4 v = *(const float4*)&part[i];
    #pragma unroll
    for (int z = 1; z < NPART; ++z) {
        float4 p = *(const float4*)&part[(size_t)z * MN + i];
        v.x += p.x; v.y += p.y; v.z += p.z; v.w += p.w;
    }
    int n = i % N;
    float4 bv = *(const float4*)&bias[n];
    float4 hv = *(const float4*)&h[i];
    v.x += bv.x + hv.x; v.y += bv.y + hv.y; v.z += bv.z + hv.z; v.w += bv.w + hv.w;
    *(float4*)&h[i] = v;
}

// ---------------- fused split-K combine + residual + LayerNorm ----------------
// h[row] = h[row] + sum_z part[z][row] + bias;  out[row] = LN(h[row])*g + be.
template <int NPART>
__global__ __launch_bounds__(256) void combine_ln(const float* __restrict__ part,
                                                  const float* __restrict__ bias,
                                                  float* __restrict__ h,
                                                  const float* __restrict__ g,
                                                  const float* __restrict__ be,
                                                  __hip_bfloat16* __restrict__ out) {
    int row = blockIdx.x, tid = threadIdx.x;
    size_t base = (size_t)row * DD;
    float a[3];
    #pragma unroll
    for (int k = 0; k < 3; ++k) {
        int j = k * 256 + tid;
        float s = part[base + j];
        #pragma unroll
        for (int z = 1; z < NPART; ++z) s += part[(size_t)z * MNTOT + base + j];
        s += bias[j] + h[base + j];
        h[base + j] = s;
        a[k] = s;
    }
    float s = a[0] + a[1] + a[2];
    #pragma unroll
    for (int o = 32; o > 0; o >>= 1) s += __shfl_down(s, o);
    __shared__ float red[4];
    if ((tid & 63) == 0) red[tid >> 6] = s;
    __syncthreads();
    float mu = (red[0] + red[1] + red[2] + red[3]) * (1.0f / 768.0f);
    float d0 = a[0] - mu, d1 = a[1] - mu, d2 = a[2] - mu;
    float q = d0 * d0 + d1 * d1 + d2 * d2;
    #pragma unroll
    for (int o = 32; o > 0; o >>= 1) q += __shfl_down(q, o);
    __syncthreads();
    if ((tid & 63) == 0) red[tid >> 6] = q;
    __syncthreads();
    float var = (red[0] + red[1] + red[2] + red[3]) * (1.0f / 768.0f);
    float rs = rsqrtf(var + 1e-6f);
    out[base + tid]       = __float2bfloat16(d0 * rs * g[tid]       + be[tid]);
    out[base + 256 + tid] = __float2bfloat16(d1 * rs * g[256 + tid] + be[256 + tid]);
    out[base + 512 + tid] = __float2bfloat16(d2 * rs * g[512 + tid] + be[512 + tid]);
}

// ---------------- classifier head: out[16][1000] = yf[16][768] @ fc_w + fc_b ----------------
// grid (8,16) = 128 blocks; m = by, n-chunk = bx*128; 128 n x 2 k-halves.
__global__ __launch_bounds__(256) void head_gemm(const float* __restrict__ yf,
                                                 const float* __restrict__ fc_w,
                                                 const float* __restrict__ fc_b,
                                                 float* __restrict__ out) {
    __shared__ float part[128];
    const int tid = threadIdx.x;
    const int nl = tid & 127, kh = tid >> 7;
    const int m = blockIdx.y;
    const int n = blockIdx.x * 128 + nl;
    float acc = 0.f;
    if (n < 1000) {
        const float* yr = yf + (size_t)m * 768 + kh * 384;
        const float* wp = fc_w + (size_t)kh * 384 * 1000 + n;
        #pragma unroll 4
        for (int k = 0; k < 384; ++k)
            acc = fmaf(yr[k], wp[(size_t)k * 1000], acc);
    }
    if (kh == 1) part[nl] = acc;
    __syncthreads();
    if (kh == 0 && n < 1000)
        out[(size_t)m * 1000 + n] = acc + part[nl] + fc_b[n];
}

// ---------------- fused flash attention (bf16 MFMA, 1 wave per block) ----------------
__global__ __launch_bounds__(64) void attn_fused(const __hip_bfloat16* __restrict__ qkv,
                                                 __hip_bfloat16* __restrict__ o) {
    __shared__ __hip_bfloat16 p_lds[32][40];
    __shared__ __hip_bfloat16 v_lds[32][68];
    const int qt = blockIdx.x, bh = blockIdx.y;
    const int b = bh / NHD, hd = bh - b * NHD;
    const int lane = threadIdx.x;
    const int l15 = lane & 15, l4 = lane >> 4;
    const size_t tb = (size_t)b * SS;
    const int hc = hd * 64;

    bf16x8 aq[2][2];
    #pragma unroll
    for (int qi = 0; qi < 2; ++qi) {
        int qr = qt * 32 + qi * 16 + l15;
        if (qr >= SS) qr = SS - 1;
        const __hip_bfloat16* qrow = qkv + (tb + qr) * 2304 + hc;
        #pragma unroll
        for (int kd = 0; kd < 2; ++kd)
            aq[qi][kd] = *(const bf16x8*)(qrow + kd * 32 + l4 * 8);
    }

    float m_run[2][4], l_run[2][4];
    f32x4 oa[2][4];
    #pragma unroll
    for (int qi = 0; qi < 2; ++qi)
        #pragma unroll
        for (int r = 0; r < 4; ++r) { m_run[qi][r] = -1e30f; l_run[qi][r] = 0.f; }
    #pragma unroll
    for (int qi = 0; qi < 2; ++qi)
        #pragma unroll
        for (int dt = 0; dt < 4; ++dt) oa[qi][dt] = (f32x4){0.f, 0.f, 0.f, 0.f};

    for (int kt = 0; kt < 10; ++kt) {
        const int kbase = kt * 32;
        bf16x4 vreg[8];
        #pragma unroll
        for (int it = 0; it < 8; ++it) {
            int vr = kbase + it * 4 + l4;
            if (vr >= SS) vr = SS - 1;
            vreg[it] = *(const bf16x4*)(qkv + (tb + vr) * 2304 + 1536 + hc + l15 * 4);
        }
        bf16x8 bk[2][2];
        #pragma unroll
        for (int ki = 0; ki < 2; ++ki) {
            int kr = kbase + ki * 16 + l15;
            if (kr >= SS) kr = SS - 1;
            const __hip_bfloat16* krow = qkv + (tb + kr) * 2304 + 768 + hc;
            #pragma unroll
            for (int kd = 0; kd < 2; ++kd)
                bk[ki][kd] = *(const bf16x8*)(krow + kd * 32 + l4 * 8);
        }
        f32x4 s[2][2];
        #pragma unroll
        for (int qi = 0; qi < 2; ++qi)
            #pragma unroll
            for (int ki = 0; ki < 2; ++ki) {
                f32x4 a = (f32x4){0.f, 0.f, 0.f, 0.f};
                #pragma unroll
                for (int kd = 0; kd < 2; ++kd)
                    a = __builtin_amdgcn_mfma_f32_16x16x32_bf16(aq[qi][kd], bk[ki][kd], a, 0, 0, 0);
                s[qi][ki] = a;
            }
        #pragma unroll
        for (int ki = 0; ki < 2; ++ki) {
            bool valid = (kbase + ki * 16 + l15) < SS;
            #pragma unroll
            for (int qi = 0; qi < 2; ++qi)
                #pragma unroll
                for (int r = 0; r < 4; ++r)
                    s[qi][ki][r] = valid ? s[qi][ki][r] * 0.125f : -1e30f;
        }
        float p[2][2][4];
        #pragma unroll
        for (int qi = 0; qi < 2; ++qi) {
            float tm[4];
            #pragma unroll
            for (int r = 0; r < 4; ++r) tm[r] = fmaxf(s[qi][0][r], s[qi][1][r]);
            #pragma unroll
            for (int sh = 1; sh < 16; sh <<= 1)
                #pragma unroll
                for (int r = 0; r < 4; ++r) tm[r] = fmaxf(tm[r], __shfl_xor(tm[r], sh));
            float rs[4];
            #pragma unroll
            for (int r = 0; r < 4; ++r) {
                float mn = fmaxf(m_run[qi][r], tm[r]);
                float corr = __expf(m_run[qi][r] - mn);
                m_run[qi][r] = mn;
                float p0 = __expf(s[qi][0][r] - mn);
                float p1 = __expf(s[qi][1][r] - mn);
                p[qi][0][r] = p0; p[qi][1][r] = p1;
                rs[r] = p0 + p1;
                l_run[qi][r] *= corr;
                #pragma unroll
                for (int dt = 0; dt < 4; ++dt) oa[qi][dt][r] *= corr;
            }
            #pragma unroll
            for (int sh = 1; sh < 16; sh <<= 1)
                #pragma unroll
                for (int r = 0; r < 4; ++r) rs[r] += __shfl_xor(rs[r], sh);
            #pragma unroll
            for (int r = 0; r < 4; ++r) l_run[qi][r] += rs[r];
        }
        #pragma unroll
        for (int qi = 0; qi < 2; ++qi)
            #pragma unroll
            for (int ki = 0; ki < 2; ++ki)
                #pragma unroll
                for (int r = 0; r < 4; ++r)
                    p_lds[qi * 16 + l4 * 4 + r][ki * 16 + l15] = __float2bfloat16(p[qi][ki][r]);
        #pragma unroll
        for (int it = 0; it < 8; ++it)
            *(bf16x4*)&v_lds[it * 4 + l4][l15 * 4] = vreg[it];
        __syncthreads();
        bf16x8 pa[2];
        #pragma unroll
        for (int qi = 0; qi < 2; ++qi)
            pa[qi] = *(const bf16x8*)&p_lds[qi * 16 + l15][l4 * 8];
        bf16x8 vb[4];
        #pragma unroll
        for (int dt = 0; dt < 4; ++dt) {
            bf16x8 v;
            #pragma unroll
            for (int j = 0; j < 8; ++j)
                v[j] = *(const short*)&v_lds[l4 * 8 + j][dt * 16 + l15];
            vb[dt] = v;
        }
        #pragma unroll
        for (int qi = 0; qi < 2; ++qi)
            #pragma unroll
            for (int dt = 0; dt < 4; ++dt)
                oa[qi][dt] = __builtin_amdgcn_mfma_f32_16x16x32_bf16(pa[qi], vb[dt], oa[qi][dt], 0, 0, 0);
        __syncthreads();
    }
    #pragma unroll
    for (int qi = 0; qi < 2; ++qi)
        #pragma unroll
        for (int r = 0; r < 4; ++r) {
            int q = qt * 32 + qi * 16 + l4 * 4 + r;
            if (q < SS) {
                float inv = 1.0f / l_run[qi][r];
                __hip_bfloat16* orow = o + (tb + q) * 768 + hc;
                #pragma unroll
                for (int dt = 0; dt < 4; ++dt)
                    orow[dt * 16 + l15] = __float2bfloat16(oa[qi][dt][r] * inv);
            }
        }
}

// ---------------- workspace layout (float offsets) ----------------
static const size_t OFF_POOLED = 0;           //  9216 f
static const size_t OFF_IDX    = 10240;       //  4608 int
static const size_t OFF_H      = 16384;       //  3,551,232 f
static const size_t OFF_YB     = 3567616;     //  3,551,232 bf16 (1,775,616 f)
static const size_t OFF_OB     = 5343232;     //  3,551,232 bf16
static const size_t OFF_QKVB   = 7118848;     // 10,653,696 bf16 (5,326,848 f)
static const size_t OFF_WBUF   = 12445696;    //  7,077,888 bf16 (3,538,944 f)
static const size_t OFF_PWB    = 15984640;    //    589,824 bf16 (294,912 f)
static const size_t OFF_YF     = 16279552;    //     12,288 f
static const size_t OFF_BIG    = 16291840;    //  7,102,464 f (col+temp / hidden)
static const size_t OFF_PART   = 23394304;    // 14,204,928 f (4 x M*N split-K partials)
// total 37,599,232 floats = 150.4 MB

extern "C" void kernel_launch(void* const* d_in, const int* in_sizes, int n_in,
                              void* d_out, int out_size, void* d_ws, size_t ws_size,
                              hipStream_t stream) {
    const float* x       = (const float*)d_in[0];
    const float* patch_w = (const float*)d_in[1];
    const float* patch_b = (const float*)d_in[2];
    const float* cls_tok = (const float*)d_in[3];
    const float* pos_emb = (const float*)d_in[4];
    const float* ln1_g   = (const float*)d_in[5];
    const float* ln1_b   = (const float*)d_in[6];
    const float* Wqkv    = (const float*)d_in[7];
    const float* bqkv    = (const float*)d_in[8];
    const float* Wo      = (const float*)d_in[9];
    const float* bo      = (const float*)d_in[10];
    const float* ln2_g   = (const float*)d_in[11];
    const float* ln2_b   = (const float*)d_in[12];
    const float* W1      = (const float*)d_in[13];
    const float* b1      = (const float*)d_in[14];
    const float* W2      = (const float*)d_in[15];
    const float* b2      = (const float*)d_in[16];
    const float* lnf_g   = (const float*)d_in[17];
    const float* lnf_b   = (const float*)d_in[18];
    const float* fc_w    = (const float*)d_in[19];
    const float* fc_b    = (const float*)d_in[20];
    float* out = (float*)d_out;
    float* ws  = (float*)d_ws;

    float*          pooled = ws + OFF_POOLED;
    int*            idxsel = (int*)(ws + OFF_IDX);
    float*          h      = ws + OFF_H;
    __hip_bfloat16* yb     = (__hip_bfloat16*)(ws + OFF_YB);
    __hip_bfloat16* ob     = (__hip_bfloat16*)(ws + OFF_OB);
    __hip_bfloat16* qkvb   = (__hip_bfloat16*)(ws + OFF_QKVB);
    __hip_bfloat16* wbuf   = (__hip_bfloat16*)(ws + OFF_WBUF);
    __hip_bfloat16* pwb    = (__hip_bfloat16*)(ws + OFF_PWB);
    float*          yf     = ws + OFF_YF;
    float*          big    = ws + OFF_BIG;
    float*          part   = ws + OFF_PART;
    __hip_bfloat16* col    = (__hip_bfloat16*)big;             // 3,538,944 bf16
    float*          temp   = big + 1769472;                    // 3,538,944 f
    __hip_bfloat16* hidden = (__hip_bfloat16*)big;             // 14,204,928 bf16

    __hip_bfloat16* wqkvT = wbuf;                              // [2304][768]
    __hip_bfloat16* woT   = wbuf + 1769472;                    // [768][768]
    __hip_bfloat16* w1T   = wbuf + 2359296;                    // [3072][768]
    __hip_bfloat16* w2T   = wbuf + 4718592;                    // [768][3072]

    const int M = BB * SS;            // 4624
    const int MG = 37;                // ceil(4624/128)
    const int MN = M * DD;            // 3,551,232

    // ---- sparse selection + patch embedding ----
    pool_kernel<<<BB * NPATCH, 256, 0, stream>>>(x, pooled);
    topk_kernel<<<BB, 576, 0, stream>>>(pooled, idxsel);
    convert_bf16<<<(589824 + 255) / 256, 256, 0, stream>>>(patch_w, pwb, 589824);
    im2col_kernel<<<BB * KSEL, 256, 0, stream>>>(x, idxsel, col);
    gemm_bf16<float, 0, 0, 1><<<dim3(3, 36), 512, 0, stream>>>(
        col, pwb, temp, patch_b, nullptr, nullptr, 4608, DD, DD);
    assemble_tokens<<<BB * SS, 256, 0, stream>>>(temp, cls_tok, pos_emb, idxsel, h);

    // ln1 for layer 0 (subsequent layers get it fused into the W2 combine)
    ln_kernel<__hip_bfloat16><<<M, 256, 0, stream>>>(h, yb, ln1_g, ln1_b, DD);

    // ---- transformer layers ----
    for (int i = 0; i < NLAY; ++i) {
        convert_layer<<<6912, 256, 0, stream>>>(Wqkv + (size_t)i * DD * 3 * DD,
                                                Wo + (size_t)i * DD * DD,
                                                W1 + (size_t)i * DD * FFD,
                                                W2 + (size_t)i * FFD * DD,
                                                wqkvT, woT, w1T, w2T);

        gemm_bf16<__hip_bfloat16, 0, 0, 1><<<dim3(9, MG), 512, 0, stream>>>(
            yb, wqkvT, qkvb, bqkv + (size_t)i * 3 * DD, nullptr, nullptr, M, 3 * DD, DD);
        // Layer 11: only q-tile 0 (cls rows) influence the output downstream —
        // non-cls rows of ob keep layer 10's values (deterministic, dead).
        attn_fused<<<dim3(i == NLAY - 1 ? 1 : 10, BB * NHD), 64, 0, stream>>>(qkvb, ob);
        // Wo: split-K x2 -> partials; fused combine(+bias+residual)+LN2 -> yb
        gemm_bf16<float, 0, 0, 2><<<dim3(3, MG, 2), 512, 0, stream>>>(
            ob, woT, (float*)nullptr, nullptr, nullptr, part, M, DD, DD);
        combine_ln<2><<<M, 256, 0, stream>>>(part, bo + (size_t)i * DD, h,
                                             ln2_g + (size_t)i * DD, ln2_b + (size_t)i * DD, yb);
        gemm_bf16<__hip_bfloat16, 1, 0, 1><<<dim3(12, MG), 512, 0, stream>>>(
            yb, w1T, hidden, b1 + (size_t)i * FFD, nullptr, nullptr, M, FFD, DD);
        // W2: split-K x4 -> partials; fused combine+LN1(next layer) -> yb
        gemm_bf16<float, 0, 0, 4><<<dim3(3, MG, 4), 512, 0, stream>>>(
            hidden, w2T, (float*)nullptr, nullptr, nullptr, part, M, DD, FFD);
        if (i + 1 < NLAY)
            combine_ln<4><<<M, 256, 0, stream>>>(part, b2 + (size_t)i * DD, h,
                                                 ln1_g + (size_t)(i + 1) * DD,
                                                 ln1_b + (size_t)(i + 1) * DD, yb);
        else
            combine_res<4><<<(MN / 4 + 255) / 256, 256, 0, stream>>>(
                part, b2 + (size_t)i * DD, h, MN, DD);
    }

    // ---- final LN on cls token + classifier head ----
    ln_kernel<float><<<BB, 256, 0, stream>>>(h, yf, lnf_g, lnf_b, (size_t)SS * DD);
    head_gemm<<<dim3(8, 16), 256, 0, stream>>>(yf, fc_w, fc_b, out);
}